// Round 3
// baseline (71.119 us; speedup 1.0000x reference)
//
#include <hip/hip_runtime.h>
#include <hip/hip_bf16.h>

// PositionEmbeddingSine: out[b,c,h,w], c in [0,256).
//   c <  128: k=c,     embed = y_embed[b,h,w]
//   c >= 128: k=c-128, embed = x_embed[b,h,w]
//   val = (k even) ? sin(embed * inv_dim_t[k]) : cos(embed * inv_dim_t[k])
//   inv_dim_t[k] = 10000^(-2*(k/2)/128)
// embeds are normalized cumsums of !mask scaled by 2*pi.

#define BATCH 32
#define HH 96
#define WW 96
#define CC 256
#define F_HALF 128

#define LOG2_TEMP 13.287712379549449f   // log2(10000)
#define TWO_PI 6.2831853071795864769f

typedef float f32x4 __attribute__((ext_vector_type(4)));

// ---------------- kernel 1: masked cumsums -> normalized embeds ----------------
// Two-pass (sum, then cumsum+scale+store): no per-thread array, no spills.
__global__ void pes_cumsum_kernel(const unsigned char* __restrict__ mask,
                                  float* __restrict__ yemb,
                                  float* __restrict__ xemb) {
    int tid = blockIdx.x * blockDim.x + threadIdx.x;
    const float eps = 1e-6f;
    if (tid < BATCH * WW) {
        // y_embed: cumsum along H for fixed (b, w). Lanes cover consecutive w
        // -> both loads and stores coalesce across the wave at every h.
        int b = tid / WW, w = tid % WW;
        const unsigned char* m = mask + (size_t)b * HH * WW + w;
        float* o = yemb + (size_t)b * HH * WW + w;
        float s = 0.f;
        for (int h = 0; h < HH; ++h) s += (m[h * WW] == 0) ? 1.f : 0.f;
        float f = TWO_PI / (s + eps);
        float cum = 0.f;
        for (int h = 0; h < HH; ++h) {
            cum += (m[h * WW] == 0) ? 1.f : 0.f;
            o[h * WW] = cum * f;
        }
    } else if (tid < 2 * BATCH * HH) {
        // x_embed: cumsum along W for fixed (b, h). Serial along w per thread.
        int t = tid - BATCH * WW;
        int b = t / HH, h = t % HH;
        const unsigned char* m = mask + ((size_t)b * HH + h) * WW;
        float* o = xemb + ((size_t)b * HH + h) * WW;
        float s = 0.f;
        for (int w = 0; w < WW; ++w) s += (m[w] == 0) ? 1.f : 0.f;
        float f = TWO_PI / (s + eps);
        float cum = 0.f;
        for (int w = 0; w < WW; ++w) {
            cum += (m[w] == 0) ? 1.f : 0.f;
            o[w] = cum * f;
        }
    }
}

// ---------------- kernel 2: generate the positional embedding ----------------
// One block per (b,c) plane: 8192 blocks x 256 threads. Everything varying
// with c (inv_dim_t, sin/cos select, embed base) is computed ONCE per thread;
// the inner loop is {float4 load (L2-hot), 4 mul, 4 trig, float4 NT store}.
#define PLANE   (HH * WW)        // 9216 floats
#define PLANE4  (PLANE / 4)      // 2304 float4
#define ITERS   (PLANE4 / 256)   // 9 per thread

__global__ void __launch_bounds__(256)
pes_gen_kernel(const float* __restrict__ yemb,
               const float* __restrict__ xemb,
               float* __restrict__ out) {
    int p = blockIdx.x;               // p in [0, BATCH*CC)
    int b = p >> 8;                   // / CC
    int c = p & (CC - 1);             // % CC

    int j = (c & (F_HALF - 1)) >> 1;
    float inv = exp2f((float)j * (-2.0f / (float)F_HALF) * LOG2_TEMP);
    bool use_sin = (c & 1) == 0;      // uniform across the block

    const f32x4* ep = (const f32x4*)((c < F_HALF ? yemb : xemb) + (size_t)b * PLANE);
    f32x4* op = (f32x4*)(out + (size_t)p * PLANE);

    int t = threadIdx.x;
#pragma unroll
    for (int it = 0; it < ITERS; ++it) {
        int idx = t + it * 256;
        f32x4 e = ep[idx];
        f32x4 r;
        if (use_sin) {
            r.x = __sinf(e.x * inv);
            r.y = __sinf(e.y * inv);
            r.z = __sinf(e.z * inv);
            r.w = __sinf(e.w * inv);
        } else {
            r.x = __cosf(e.x * inv);
            r.y = __cosf(e.y * inv);
            r.z = __cosf(e.z * inv);
            r.w = __cosf(e.w * inv);
        }
        __builtin_nontemporal_store(r, op + idx);
    }
}

extern "C" void kernel_launch(void* const* d_in, const int* in_sizes, int n_in,
                              void* d_out, int out_size, void* d_ws, size_t ws_size,
                              hipStream_t stream) {
    // inputs: d_in[0] = x (unused, dtype carrier), d_in[1] = mask (bool, 32*96*96)
    const unsigned char* mask = (const unsigned char*)d_in[1];
    float* out = (float*)d_out;

    // workspace: yemb then xemb, each BATCH*HH*WW floats (1.18 MB each)
    float* yemb = (float*)d_ws;
    float* xemb = yemb + (size_t)BATCH * PLANE;

    // kernel 1: 2*32*96 = 6144 threads
    {
        int threads = 2 * BATCH * HH;
        int block = 256;
        int grid = (threads + block - 1) / block;
        pes_cumsum_kernel<<<grid, block, 0, stream>>>(mask, yemb, xemb);
    }

    // kernel 2: one block per (b,c) output plane
    pes_gen_kernel<<<BATCH * CC, 256, 0, stream>>>(yemb, xemb, out);
}

// Round 4
// 60.998 us; speedup vs baseline: 1.1659x; 1.1659x over previous
//
#include <hip/hip_runtime.h>
#include <hip/hip_bf16.h>

// PositionEmbeddingSine: out[b,c,h,w], c in [0,256).
//   c <  128: k=c,     embed = y_embed[b,h,w]
//   c >= 128: k=c-128, embed = x_embed[b,h,w]
//   val = (k even) ? sin(embed * inv_dim_t[k]) : cos(embed * inv_dim_t[k])
//   inv_dim_t[k] = 10000^(-2*(k/2)/128)
// Channel pair (2j, 2j+1) shares the angle -> one block emits both planes.

#define BATCH 32
#define HH 96
#define WW 96
#define CC 256
#define F_HALF 128

#define LOG2_TEMP 13.287712379549449f   // log2(10000)
#define TWO_PI 6.2831853071795864769f

typedef float f32x4 __attribute__((ext_vector_type(4)));

// ---------------- kernel 1: masked cumsums -> normalized embeds ----------------
__global__ void pes_cumsum_kernel(const unsigned char* __restrict__ mask,
                                  float* __restrict__ yemb,
                                  float* __restrict__ xemb) {
    int tid = blockIdx.x * blockDim.x + threadIdx.x;
    const float eps = 1e-6f;
    if (tid < BATCH * WW) {
        // y_embed: cumsum along H for fixed (b, w); lanes over w -> coalesced.
        int b = tid / WW, w = tid % WW;
        const unsigned char* m = mask + (size_t)b * HH * WW + w;
        float* o = yemb + (size_t)b * HH * WW + w;
        float s = 0.f;
        for (int h = 0; h < HH; ++h) s += (m[h * WW] == 0) ? 1.f : 0.f;
        float f = TWO_PI / (s + eps);
        float cum = 0.f;
        for (int h = 0; h < HH; ++h) {
            cum += (m[h * WW] == 0) ? 1.f : 0.f;
            o[h * WW] = cum * f;
        }
    } else if (tid < 2 * BATCH * HH) {
        // x_embed: cumsum along W for fixed (b, h).
        int t = tid - BATCH * WW;
        int b = t / HH, h = t % HH;
        const unsigned char* m = mask + ((size_t)b * HH + h) * WW;
        float* o = xemb + ((size_t)b * HH + h) * WW;
        float s = 0.f;
        for (int w = 0; w < WW; ++w) s += (m[w] == 0) ? 1.f : 0.f;
        float f = TWO_PI / (s + eps);
        float cum = 0.f;
        for (int w = 0; w < WW; ++w) {
            cum += (m[w] == 0) ? 1.f : 0.f;
            o[w] = cum * f;
        }
    }
}

// ---------------- kernel 2: generate the positional embedding ----------------
// One block per (b, channel-pair): 32*128 = 4096 blocks x 256 threads.
// Pair (c=2j -> sin, c=2j+1 -> cos) shares angle = embed * inv_dim_t.
// Inner loop: 1 f32x4 load (L2-hot), 4 mul, 4 sin + 4 cos, 2 f32x4 stores.
#define PLANE   (HH * WW)        // 9216 floats
#define PLANE4  (PLANE / 4)      // 2304 float4
#define ITERS   (PLANE4 / 256)   // 9 per thread

__global__ void __launch_bounds__(256)
pes_gen_kernel(const float* __restrict__ yemb,
               const float* __restrict__ xemb,
               float* __restrict__ out) {
    int p = blockIdx.x;               // p in [0, BATCH*F_HALF)
    int b = p >> 7;                   // / 128 pairs
    int j = p & 127;                  // pair index; c = 2j, 2j+1

    int jj = j & 63;                  // k>>1 within the half
    float inv = exp2f((float)jj * (-2.0f / (float)F_HALF) * LOG2_TEMP);

    const float* embbase = (j < 64) ? yemb : xemb;   // c<128 <-> j<64
    const f32x4* ep = (const f32x4*)(embbase + (size_t)b * PLANE);
    f32x4* op0 = (f32x4*)(out + ((size_t)b * CC + 2 * j) * PLANE);      // sin plane
    f32x4* op1 = op0 + PLANE4;                                          // cos plane

    int t = threadIdx.x;
#pragma unroll
    for (int it = 0; it < ITERS; ++it) {
        int idx = t + it * 256;
        f32x4 e = ep[idx];
        f32x4 a;
        a.x = e.x * inv; a.y = e.y * inv; a.z = e.z * inv; a.w = e.w * inv;
        f32x4 rs, rc;
        rs.x = __sinf(a.x); rs.y = __sinf(a.y); rs.z = __sinf(a.z); rs.w = __sinf(a.w);
        rc.x = __cosf(a.x); rc.y = __cosf(a.y); rc.z = __cosf(a.z); rc.w = __cosf(a.w);
        op0[idx] = rs;
        op1[idx] = rc;
    }
}

extern "C" void kernel_launch(void* const* d_in, const int* in_sizes, int n_in,
                              void* d_out, int out_size, void* d_ws, size_t ws_size,
                              hipStream_t stream) {
    // inputs: d_in[0] = x (unused, dtype carrier), d_in[1] = mask (bool, 32*96*96)
    const unsigned char* mask = (const unsigned char*)d_in[1];
    float* out = (float*)d_out;

    // workspace: yemb then xemb, each BATCH*HH*WW floats (1.18 MB each)
    float* yemb = (float*)d_ws;
    float* xemb = yemb + (size_t)BATCH * PLANE;

    // kernel 1: 2*32*96 = 6144 threads
    {
        int threads = 2 * BATCH * HH;
        int block = 256;
        int grid = (threads + block - 1) / block;
        pes_cumsum_kernel<<<grid, block, 0, stream>>>(mask, yemb, xemb);
    }

    // kernel 2: one block per (batch, channel-pair)
    pes_gen_kernel<<<BATCH * F_HALF, 256, 0, stream>>>(yemb, xemb, out);
}

// Round 5
// 52.832 us; speedup vs baseline: 1.3461x; 1.1546x over previous
//
#include <hip/hip_runtime.h>
#include <hip/hip_bf16.h>

// PositionEmbeddingSine, fully fused: out[b,c,h,w], c in [0,256).
//   c <  128: k=c,     embed = y_embed[b,h,w]   (cumsum of !mask along H, norm'd)
//   c >= 128: k=c-128, embed = x_embed[b,h,w]   (cumsum of !mask along W, norm'd)
//   val = (k even) ? sin(embed * inv_dim_t[k]) : cos(embed * inv_dim_t[k])
//   inv_dim_t[k] = 10000^(-2*(k/2)/128)
// One block per (b, channel-pair): pair (2j, 2j+1) shares the angle.
// The block recomputes its 96x96 embed plane from the mask into LDS (cheap,
// mask is L2-hot), then streams 2 planes of sin/cos out. Single dispatch.

#define BATCH 32
#define HH 96
#define WW 96
#define CC 256
#define F_HALF 128
#define PLANE   (HH * WW)        // 9216
#define PLANE4  (PLANE / 4)      // 2304
#define ITERS   (PLANE4 / 256)   // 9
#define PITCH   100              // LDS row pitch in floats: 400 B (16B-aligned),
                                 // breaks the 64-way bank conflict of pitch 96

#define LOG2_TEMP 13.287712379549449f   // log2(10000)
#define TWO_PI 6.2831853071795864769f

typedef float f32x4 __attribute__((ext_vector_type(4)));

__global__ void __launch_bounds__(256)
pes_fused_kernel(const unsigned char* __restrict__ mask,
                 float* __restrict__ out) {
    __shared__ float emb[HH * PITCH];   // 37.5 KB -> 4 blocks/CU

    int p = blockIdx.x;               // [0, BATCH*F_HALF)
    int b = p >> 7;                   // batch
    int j = p & 127;                  // pair index; channels 2j, 2j+1
    int jj = j & 63;                  // k>>1 within the half

    float inv = exp2f((float)jj * (-2.0f / (float)F_HALF) * LOG2_TEMP);
    const unsigned char* mb = mask + (size_t)b * PLANE;
    int t = threadIdx.x;
    const float eps = 1e-6f;

    // ---- build the embed plane in LDS (96 threads, rest wait) ----
    if (j < 64) {
        // y_embed: cumsum along H at fixed column w = t. Lane w reads
        // consecutive bytes at each h -> coalesced; mask plane is L2/L1-hot.
        if (t < WW) {
            int w = t;
            float s = 0.f;
            for (int h = 0; h < HH; ++h) s += (mb[h * WW + w] == 0) ? 1.f : 0.f;
            float f = TWO_PI / (s + eps);
            float cum = 0.f;
            for (int h = 0; h < HH; ++h) {
                cum += (mb[h * WW + w] == 0) ? 1.f : 0.f;
                emb[h * PITCH + w] = cum * f;   // bank (4h+w)%32: conflict-free
            }
        }
    } else {
        // x_embed: cumsum along W at fixed row h = t (serial per thread).
        if (t < HH) {
            int h = t;
            const unsigned char* mr = mb + h * WW;
            float s = 0.f;
            for (int w = 0; w < WW; ++w) s += (mr[w] == 0) ? 1.f : 0.f;
            float f = TWO_PI / (s + eps);
            float cum = 0.f;
            for (int w = 0; w < WW; ++w) {
                cum += (mr[w] == 0) ? 1.f : 0.f;
                emb[h * PITCH + w] = cum * f;   // 8-way conflict (pitch 100), ~300 cy total
            }
        }
    }
    __syncthreads();

    // ---- stream out sin plane (c=2j) and cos plane (c=2j+1) ----
    f32x4* op0 = (f32x4*)(out + ((size_t)b * CC + 2 * j) * PLANE);
    f32x4* op1 = op0 + PLANE4;

#pragma unroll
    for (int it = 0; it < ITERS; ++it) {
        int idx = t + it * 256;          // f32x4 index within the plane
        int h = idx / 24;                // 24 f32x4 per row
        int k = idx - h * 24;
        f32x4 e = *(const f32x4*)&emb[h * PITCH + 4 * k];
        f32x4 a;
        a.x = e.x * inv; a.y = e.y * inv; a.z = e.z * inv; a.w = e.w * inv;
        f32x4 rs, rc;
        rs.x = __sinf(a.x); rs.y = __sinf(a.y); rs.z = __sinf(a.z); rs.w = __sinf(a.w);
        rc.x = __cosf(a.x); rc.y = __cosf(a.y); rc.z = __cosf(a.z); rc.w = __cosf(a.w);
        op0[idx] = rs;
        op1[idx] = rc;
    }
}

extern "C" void kernel_launch(void* const* d_in, const int* in_sizes, int n_in,
                              void* d_out, int out_size, void* d_ws, size_t ws_size,
                              hipStream_t stream) {
    // inputs: d_in[0] = x (unused, dtype carrier), d_in[1] = mask (bool, 32*96*96)
    const unsigned char* mask = (const unsigned char*)d_in[1];
    float* out = (float*)d_out;

    // single fused dispatch: one block per (batch, channel-pair)
    pes_fused_kernel<<<BATCH * F_HALF, 256, 0, stream>>>(mask, out);
}